// Round 1
// baseline (640.876 us; speedup 1.0000x reference)
//
#include <hip/hip_runtime.h>
#include <cstdint>

#define BB 16
#define MM 128
#define TT 12000
constexpr int BT = BB * TT; // 192000

// K1: per-column stats over the M axis, sequential in m to match numpy's
// non-innermost-axis reduction order. asm barriers block fma contraction.
__global__ void k1_colstats(const float* __restrict__ mel,
                            float* __restrict__ ssq,
                            float* __restrict__ dotv,
                            float* __restrict__ cmean) {
    const int b = blockIdx.y;
    const int t = blockIdx.x * blockDim.x + threadIdx.x;
    const bool valid = t < TT;
    const float* base = mel + (size_t)b * MM * TT;
    const int lane = threadIdx.x & 63;
    float accd = 0.f, accq = 0.f, accs = 0.f;
    for (int m = 0; m < MM; ++m) {
        const float* rowp = base + (size_t)m * TT;
        float cur = valid ? rowp[t] : 0.f;
        float prev = __shfl_up(cur, 1);
        if (lane == 0) prev = (valid && t > 0) ? rowp[t - 1] : 0.f;
        float p = prev * cur; asm volatile("" : "+v"(p));
        accd += p;
        float q = cur * cur;  asm volatile("" : "+v"(q));
        accq += q;
        accs += cur;
    }
    if (valid) {
        size_t i = (size_t)b * TT + t;
        ssq[i] = accq; dotv[i] = accd; cmean[i] = accs * (1.0f / MM);
    }
}

// K2: temporal = 1 - std(smooth, ddof=1); ordering mismatch washed out by
// sqrt compression (delta ~1e-9), so a plain two-pass tree reduce is fine.
__global__ void k2_temporal(const float* __restrict__ cmean,
                            float* __restrict__ temporal) {
    const int b = blockIdx.x;
    const float* row = cmean + (size_t)b * TT;
    __shared__ float red[256];
    __shared__ float mean_s;
    float s = 0.f;
    for (int t = threadIdx.x; t < TT; t += 256) {
        float v = 0.f;
        int lo = t - 2 < 0 ? 0 : t - 2;
        int hi = t + 2 >= TT ? TT - 1 : t + 2;
        for (int j = lo; j <= hi; ++j) v += row[j];
        s += v / 5.0f;
    }
    red[threadIdx.x] = s; __syncthreads();
    for (int o = 128; o > 0; o >>= 1) {
        if (threadIdx.x < o) red[threadIdx.x] += red[threadIdx.x + o];
        __syncthreads();
    }
    if (threadIdx.x == 0) mean_s = red[0] / (float)TT;
    __syncthreads();
    float mean = mean_s;
    float ss = 0.f;
    for (int t = threadIdx.x; t < TT; t += 256) {
        float v = 0.f;
        int lo = t - 2 < 0 ? 0 : t - 2;
        int hi = t + 2 >= TT ? TT - 1 : t + 2;
        for (int j = lo; j <= hi; ++j) v += row[j];
        float sm = v / 5.0f - mean;
        ss += sm * sm;
    }
    red[threadIdx.x] = ss; __syncthreads();
    for (int o = 128; o > 0; o >>= 1) {
        if (threadIdx.x < o) red[threadIdx.x] += red[threadIdx.x + o];
        __syncthreads();
    }
    if (threadIdx.x == 0) {
        float var = red[0] / (float)(TT - 1);
        temporal[b] = 1.0f - sqrtf(var);
    }
}

// K3: cons = w0*mel_sim + w1*spec_sim + w2*temporal, replicating the
// reference's exact elementwise expression (no fma contraction).
__global__ void k3_cons(const float* __restrict__ ssq,
                        const float* __restrict__ dotv,
                        const float* __restrict__ spec,
                        const float* __restrict__ temporal,
                        const float* __restrict__ wraw,
                        float* __restrict__ cons) {
    const int idx = blockIdx.x * 256 + threadIdx.x;
    const int b = idx / TT;
    const int t = idx - b * TT;
    float x0 = wraw[0], x1 = wraw[1], x2 = wraw[2];
    float mx = fmaxf(x0, fmaxf(x1, x2));
    float e0 = expf(x0 - mx), e1 = expf(x1 - mx), e2 = expf(x2 - mx);
    float es = (e0 + e1) + e2;
    float w0 = e0 / es, w1 = e1 / es, w2 = e2 / es;
    float mel_sim, spec_sim;
    if (t == 0) { mel_sim = 0.f; spec_sim = 1.f; }
    else {
        float na = fmaxf(sqrtf(ssq[idx - 1]), 1e-8f);
        float nb = fmaxf(sqrtf(ssq[idx]),     1e-8f);
        float den = na * nb; asm volatile("" : "+v"(den));
        mel_sim = dotv[idx] / den;
        float d = fabsf(spec[idx] - spec[idx - 1]);
        spec_sim = 1.0f / (1.0f + d);
    }
    float pa = w0 * mel_sim;     asm volatile("" : "+v"(pa));
    float pb = w1 * spec_sim;    asm volatile("" : "+v"(pb));
    float pc = w2 * temporal[b]; asm volatile("" : "+v"(pc));
    cons[idx] = (pa + pb) + pc;
}

// K4: bitwise replication of numpy's sequential float32 cumsum per row.
// Latency-bound serial chain; 16 rows run in parallel lanes of one wave.
__global__ void k4_cumsum(const float* __restrict__ cons,
                          float* __restrict__ CS) {
    const int b = threadIdx.x;
    if (b >= BB) return;
    const float* row = cons + (size_t)b * TT;
    float* out = CS + (size_t)b * (TT + 1);
    out[0] = 0.f;
    float acc = 0.f;
#pragma unroll 8
    for (int i = 0; i < TT; ++i) { acc += row[i]; out[i + 1] = acc; }
}

// K5: per-element static quantities + never-done 5-iter trajectory;
// exact integer counts of nonzero adjustments per iteration.
__global__ void k5_prepare(const float* __restrict__ cons,
                           const float* __restrict__ CS,
                           const float* __restrict__ init,
                           float* __restrict__ stepv,
                           float* __restrict__ candf,
                           unsigned int* __restrict__ counts) {
    const int idx = blockIdx.x * 256 + threadIdx.x;
    const int b = idx / TT;
    const int t = idx - b * TT;
    const float* cs = CS + (size_t)b * (TT + 1);
    int lo = t - 2; if (lo < 0) lo = 0;
    int hi = t + 3; if (hi > TT) hi = TT;
    float local = (cs[hi] - cs[lo]) / (float)(hi - lo);
    float dir = (local > 0.7f) ? -0.1f : ((local < 0.4f) ? 0.1f : 0.0f);
    bool interior = (t >= 1) && (t <= TT - 2);
    float step = interior ? dir : 0.0f;
    float g = (t == 0) ? 0.f : fabsf(cons[idx] - cons[idx - 1]);
    float cand = (g > 0.15f) ? 1.f : 0.f;
    float r = init[idx];
    bool nz[5];
#pragma unroll
    for (int j = 0; j < 5; ++j) {
        float adj = (fmaxf(cand, r) > 0.5f) ? step : 0.0f;
        nz[j] = (adj != 0.0f);
        r = fminf(fmaxf(r + adj, 0.0f), 1.0f);
    }
    stepv[idx] = step; candf[idx] = cand;
    const int lane = threadIdx.x & 63;
#pragma unroll
    for (int j = 0; j < 5; ++j) {
        unsigned long long mb = __ballot(nz[j]);
        if (lane == 0) atomicAdd(&counts[j], (unsigned)__popcll(mb));
    }
}

// K6: freeze at the first iteration whose global adjustment count is zero.
__global__ void k6_final(const float* __restrict__ init,
                         const float* __restrict__ stepv,
                         const float* __restrict__ candf,
                         const unsigned int* __restrict__ counts,
                         float* __restrict__ outp) {
    const int idx = blockIdx.x * 256 + threadIdx.x;
    float r = init[idx];
    float step = stepv[idx];
    float cand = candf[idx];
    unsigned c[5];
#pragma unroll
    for (int j = 0; j < 5; ++j) c[j] = counts[j];
#pragma unroll
    for (int j = 0; j < 5; ++j) {
        if (c[j] == 0u) break;
        float adj = (fmaxf(cand, r) > 0.5f) ? step : 0.0f;
        r = fminf(fmaxf(r + adj, 0.0f), 1.0f);
    }
    outp[idx] = r;
}

extern "C" void kernel_launch(void* const* d_in, const int* in_sizes, int n_in,
                              void* d_out, int out_size, void* d_ws, size_t ws_size,
                              hipStream_t stream) {
    const float* mel  = (const float*)d_in[0];
    const float* spec = (const float*)d_in[1];
    const float* init = (const float*)d_in[2];
    const float* wts  = (const float*)d_in[3];

    float* ws = (float*)d_ws;
    float* ssq      = ws;                 // 192000
    float* dotv     = ws + 192000;        // 192000
    float* cmean    = ws + 384000;        // 192000
    float* cons     = ws + 576000;        // 192000
    float* CS       = ws + 768000;        // 16*12001 = 192016
    float* stepv    = ws + 960016;        // 192000
    float* candf    = ws + 1152016;       // 192000
    float* temporal = ws + 1344016;       // 16
    unsigned int* counts = (unsigned int*)(ws + 1344032); // 8 u32

    hipMemsetAsync(counts, 0, 8 * sizeof(unsigned int), stream);

    dim3 g1((TT + 255) / 256, BB);
    k1_colstats<<<g1, 256, 0, stream>>>(mel, ssq, dotv, cmean);
    k2_temporal<<<BB, 256, 0, stream>>>(cmean, temporal);
    k3_cons<<<BT / 256, 256, 0, stream>>>(ssq, dotv, spec, temporal, wts, cons);
    k4_cumsum<<<1, 64, 0, stream>>>(cons, CS);
    k5_prepare<<<BT / 256, 256, 0, stream>>>(cons, CS, init, stepv, candf, counts);
    k6_final<<<BT / 256, 256, 0, stream>>>(init, stepv, candf, counts, (float*)d_out);
}

// Round 2
// 243.322 us; speedup vs baseline: 2.6339x; 2.6339x over previous
//
#include <hip/hip_runtime.h>
#include <cstdint>

#define BB 16
#define MM 128
#define TT 12000
constexpr int BT = BB * TT; // 192000

// K1: per-column stats over the M axis, sequential in m to match the
// reference reduction order. asm barriers block fma contraction.
// prev now loaded directly (value-identical to the shfl version, no
// per-iteration divergent lane-0 load).
__global__ void k1_colstats(const float* __restrict__ mel,
                            float* __restrict__ ssq,
                            float* __restrict__ dotv,
                            float* __restrict__ cmean) {
    const int b = blockIdx.y;
    const int t = blockIdx.x * blockDim.x + threadIdx.x;
    if (t >= TT) return;
    const float* base = mel + (size_t)b * MM * TT;
    float accd = 0.f, accq = 0.f, accs = 0.f;
#pragma unroll 4
    for (int m = 0; m < MM; ++m) {
        const float* rowp = base + (size_t)m * TT;
        float cur = rowp[t];
        float prev = (t > 0) ? rowp[t - 1] : 0.f;
        float p = prev * cur; asm volatile("" : "+v"(p));
        accd += p;
        float q = cur * cur;  asm volatile("" : "+v"(q));
        accq += q;
        accs += cur;
    }
    size_t i = (size_t)b * TT + t;
    ssq[i] = accq; dotv[i] = accd; cmean[i] = accs * (1.0f / MM);
}

// K_row: one block per row. Fuses temporal (old k2), cons (old k3),
// serial cumsum (old k4, now LDS-resident in-place), and the
// local/step/cand/5-iter simulation (old k5). All arithmetic orders
// are kept bitwise identical to the previously passing kernels.
__global__ void __launch_bounds__(256)
k_row(const float* __restrict__ ssq,
      const float* __restrict__ dotv,
      const float* __restrict__ spec,
      const float* __restrict__ cmean,
      const float* __restrict__ wraw,
      const float* __restrict__ init,
      float* __restrict__ stepv,
      float* __restrict__ candf,
      unsigned int* __restrict__ counts) {
    const int b = blockIdx.x;
    const int tid = threadIdx.x;
    __shared__ __align__(16) float buf[TT];   // cmean -> cons -> incl-cumsum (in place)
    __shared__ float red[256];
    __shared__ float mean_s, temp_s;
    __shared__ unsigned scnt[5];

    // ---- Phase A: stage cmean row, temporal = 1 - std(smooth, ddof=1) ----
    const float* crow = cmean + (size_t)b * TT;
    for (int t = tid; t < TT; t += 256) buf[t] = crow[t];
    if (tid < 5) scnt[tid] = 0u;
    __syncthreads();

    float s = 0.f;
    for (int t = tid; t < TT; t += 256) {
        float v = 0.f;
        int lo = t - 2 < 0 ? 0 : t - 2;
        int hi = t + 2 >= TT ? TT - 1 : t + 2;
        for (int j = lo; j <= hi; ++j) v += buf[j];
        s += v / 5.0f;
    }
    red[tid] = s; __syncthreads();
    for (int o = 128; o > 0; o >>= 1) {
        if (tid < o) red[tid] += red[tid + o];
        __syncthreads();
    }
    if (tid == 0) mean_s = red[0] / (float)TT;
    __syncthreads();
    float mean = mean_s;
    float ss = 0.f;
    for (int t = tid; t < TT; t += 256) {
        float v = 0.f;
        int lo = t - 2 < 0 ? 0 : t - 2;
        int hi = t + 2 >= TT ? TT - 1 : t + 2;
        for (int j = lo; j <= hi; ++j) v += buf[j];
        float sm = v / 5.0f - mean;
        ss += sm * sm;
    }
    red[tid] = ss; __syncthreads();
    for (int o = 128; o > 0; o >>= 1) {
        if (tid < o) red[tid] += red[tid + o];
        __syncthreads();
    }
    if (tid == 0) {
        float var = red[0] / (float)(TT - 1);
        temp_s = 1.0f - sqrtf(var);
    }
    __syncthreads();

    // ---- Phase B: cons row into buf (overwrite cmean), cand bits in regs ----
    float x0 = wraw[0], x1 = wraw[1], x2 = wraw[2];
    float mx = fmaxf(x0, fmaxf(x1, x2));
    float e0 = expf(x0 - mx), e1 = expf(x1 - mx), e2 = expf(x2 - mx);
    float es = (e0 + e1) + e2;
    float w0 = e0 / es, w1 = e1 / es, w2 = e2 / es;
    float temporal = temp_s;

    const float* sqr = ssq  + (size_t)b * TT;
    const float* dtr = dotv + (size_t)b * TT;
    const float* spr = spec + (size_t)b * TT;
    for (int t = tid; t < TT; t += 256) {
        float mel_sim, spec_sim;
        if (t == 0) { mel_sim = 0.f; spec_sim = 1.f; }
        else {
            float na = fmaxf(sqrtf(sqr[t - 1]), 1e-8f);
            float nb = fmaxf(sqrtf(sqr[t]),     1e-8f);
            float den = na * nb; asm volatile("" : "+v"(den));
            mel_sim = dtr[t] / den;
            float d = fabsf(spr[t] - spr[t - 1]);
            spec_sim = 1.0f / (1.0f + d);
        }
        float pa = w0 * mel_sim;  asm volatile("" : "+v"(pa));
        float pb = w1 * spec_sim; asm volatile("" : "+v"(pb));
        float pc = w2 * temporal; asm volatile("" : "+v"(pc));
        buf[t] = (pa + pb) + pc;
    }
    __syncthreads();

    unsigned long long candbits = 0ull;
    {
        int k = 0;
        for (int t = tid; t < TT; t += 256, ++k) {
            float g = (t == 0) ? 0.f : fabsf(buf[t] - buf[t - 1]);
            if (g > 0.15f) candbits |= (1ull << k);
        }
    }
    __syncthreads();

    // ---- Phase C: serial in-place inclusive cumsum (bitwise f32 chain) ----
    if (tid == 0) {
        float4* p4 = (float4*)buf;
        float acc = 0.f;
#pragma unroll 4
        for (int i = 0; i < TT / 4; ++i) {
            float4 v = p4[i];
            acc += v.x; v.x = acc;
            acc += v.y; v.y = acc;
            acc += v.z; v.z = acc;
            acc += v.w; v.w = acc;
            p4[i] = v;
        }
    }
    __syncthreads();

    // ---- Phase D: local/step + 5-iter never-done sim + exact counts ----
    const float* irow = init + (size_t)b * TT;
    unsigned nzc[5] = {0u, 0u, 0u, 0u, 0u};
    {
        int k = 0;
        for (int t = tid; t < TT; t += 256, ++k) {
            int lo = t - 2; if (lo < 0) lo = 0;
            int hi = t + 3; if (hi > TT) hi = TT;
            float csH = buf[hi - 1];                       // == old CS[hi]
            float csL = (lo > 0) ? buf[lo - 1] : 0.f;      // == old CS[lo]
            float local = (csH - csL) / (float)(hi - lo);
            float dir = (local > 0.7f) ? -0.1f : ((local < 0.4f) ? 0.1f : 0.0f);
            bool interior = (t >= 1) && (t <= TT - 2);
            float step = interior ? dir : 0.0f;
            float cand = ((candbits >> k) & 1ull) ? 1.f : 0.f;
            float r = irow[t];
#pragma unroll
            for (int j = 0; j < 5; ++j) {
                float adj = (fmaxf(cand, r) > 0.5f) ? step : 0.0f;
                if (adj != 0.0f) nzc[j]++;
                r = fminf(fmaxf(r + adj, 0.0f), 1.0f);
            }
            size_t idx = (size_t)b * TT + t;
            stepv[idx] = step; candf[idx] = cand;
        }
    }
#pragma unroll
    for (int j = 0; j < 5; ++j) {
        if (nzc[j]) atomicAdd(&scnt[j], nzc[j]);
    }
    __syncthreads();
    if (tid < 5 && scnt[tid]) atomicAdd(&counts[tid], scnt[tid]);
}

// K_final: freeze at the first iteration whose global adjustment count is 0.
__global__ void k_final(const float* __restrict__ init,
                        const float* __restrict__ stepv,
                        const float* __restrict__ candf,
                        const unsigned int* __restrict__ counts,
                        float* __restrict__ outp) {
    const int idx = blockIdx.x * 256 + threadIdx.x;
    float r = init[idx];
    float step = stepv[idx];
    float cand = candf[idx];
    unsigned c[5];
#pragma unroll
    for (int j = 0; j < 5; ++j) c[j] = counts[j];
#pragma unroll
    for (int j = 0; j < 5; ++j) {
        if (c[j] == 0u) break;
        float adj = (fmaxf(cand, r) > 0.5f) ? step : 0.0f;
        r = fminf(fmaxf(r + adj, 0.0f), 1.0f);
    }
    outp[idx] = r;
}

extern "C" void kernel_launch(void* const* d_in, const int* in_sizes, int n_in,
                              void* d_out, int out_size, void* d_ws, size_t ws_size,
                              hipStream_t stream) {
    const float* mel  = (const float*)d_in[0];
    const float* spec = (const float*)d_in[1];
    const float* init = (const float*)d_in[2];
    const float* wts  = (const float*)d_in[3];

    float* ws = (float*)d_ws;
    float* ssq   = ws;                 // 192000
    float* dotv  = ws + 192000;        // 192000
    float* cmean = ws + 384000;        // 192000
    float* stepv = ws + 576000;        // 192000
    float* candf = ws + 768000;        // 192000
    unsigned int* counts = (unsigned int*)(ws + 960000); // 8 u32

    hipMemsetAsync(counts, 0, 8 * sizeof(unsigned int), stream);

    dim3 g1((TT + 255) / 256, BB);
    k1_colstats<<<g1, 256, 0, stream>>>(mel, ssq, dotv, cmean);
    k_row<<<BB, 256, 0, stream>>>(ssq, dotv, spec, cmean, wts, init,
                                  stepv, candf, counts);
    k_final<<<BT / 256, 256, 0, stream>>>(init, stepv, candf, counts, (float*)d_out);
}